// Round 5
// baseline (1140.435 us; speedup 1.0000x reference)
//
#include <hip/hip_runtime.h>
#include <hip/hip_bf16.h>
#include <math.h>

#define T_TOK 8192
#define DH 1024
#define DFFN 4096
#define NEXP 8
#define MAXT 136           // 128-row tiles (ffn2): 8 XCD-chunks of 17
#define MAXT256 72         // 256-row tiles (ffn1): 8 XCD-chunks of 9
#define MAXROWS 18432      // max padded row slots (256-aligned per expert)

typedef __attribute__((ext_vector_type(8))) short short8;
typedef __attribute__((ext_vector_type(4))) float f32x4;
typedef __attribute__((ext_vector_type(4))) unsigned short ushortx4;

typedef const __attribute__((address_space(1))) void* gp1_t;
typedef __attribute__((address_space(3))) void* lp3_t;

__device__ __forceinline__ void gl_lds16(const void* g, void* l) {
    __builtin_amdgcn_global_load_lds((gp1_t)g, (lp3_t)l, 16, 0, 0);
}

__device__ __forceinline__ int swz(int r) { return (r ^ (r >> 2)) & 3; }

__device__ __forceinline__ unsigned short f2bf(float f) {
    unsigned u = __float_as_uint(f);
    u += 0x7fffu + ((u >> 16) & 1u);   // RNE
    return (unsigned short)(u >> 16);
}

// s_waitcnt immediates (gfx9 encoding): vm low nibble (+bits15:14), exp bits 4-6, lgkm bits 8-11
#define WAITCNT_VM4   0xF74
#define WAITCNT_VM0   0xF70
#define WAITCNT_LGKM0 0xC07F

// ---------------- ws header layout (ints) ----------------
// hdr[0] n_tiles256 | hdr[1] n_tiles128 | hdr[8..15] cnt | hdr[16..23] cursor
// hdr[24..31] pbase | hdr[32..39] esum(float)
// hdr[64..]  map256[MAXT256]: e | valid<<4 (9b) | base<<16
// hdr[256..] map128[MAXT]:    e | valid<<4 (8b) | base<<16
#define WS_IDX     4096
#define WS_WPAIR   (WS_IDX + 65536)
#define WS_SLOT    (WS_WPAIR + 65536)
#define WS_ROWTOK  (WS_SLOT + 65536)
#define WS_ROWW    (WS_ROWTOK + 4*MAXROWS)
#define WS_XB      524288               // bf16[8192][1024] = 16 MB

// ---------------- gating: one wave per token; also emits x as bf16 ----------------
__global__ __launch_bounds__(256) void gate_kernel(
        const float* __restrict__ x, const float* __restrict__ Wg,
        int* __restrict__ hdr, float* __restrict__ esum,
        int* __restrict__ idx_pair, float* __restrict__ w_pair,
        unsigned short* __restrict__ Xb) {
    int wid = threadIdx.x >> 6, lane = threadIdx.x & 63;
    int t = blockIdx.x * 4 + wid;
    const float4* xv = (const float4*)(x + (size_t)t * DH);
    const float4* wv = (const float4*)Wg;
    float acc[NEXP];
#pragma unroll
    for (int e = 0; e < NEXP; e++) acc[e] = 0.f;
#pragma unroll
    for (int c = 0; c < 4; c++) {
        int fi = c * 64 + lane;
        float4 xe = xv[fi];
        ushortx4 p;
        p[0] = f2bf(xe.x); p[1] = f2bf(xe.y); p[2] = f2bf(xe.z); p[3] = f2bf(xe.w);
        *(ushortx4*)(Xb + (size_t)t * DH + fi * 4) = p;
#pragma unroll
        for (int e = 0; e < NEXP; e++) {
            float4 we = wv[e * 256 + fi];
            acc[e] += xe.x * we.x + xe.y * we.y + xe.z * we.z + xe.w * we.w;
        }
    }
#pragma unroll
    for (int e = 0; e < NEXP; e++) {
#pragma unroll
        for (int off = 32; off > 0; off >>= 1)
            acc[e] += __shfl_xor(acc[e], off, 64);
    }
    if (lane == 0) {
        float v0 = -1e30f, v1 = -1e30f;
        int i0 = 0, i1 = 0;
#pragma unroll
        for (int e = 0; e < NEXP; e++) {
            float l = acc[e];
            if (l > v0) { v1 = v0; i1 = i0; v0 = l; i0 = e; }
            else if (l > v1) { v1 = l; i1 = e; }
        }
        float e1 = __expf(v1 - v0);
        float w0 = 1.0f / (1.0f + e1);
        float w1 = e1 / (1.0f + e1);
        idx_pair[2 * t] = i0; idx_pair[2 * t + 1] = i1;
        w_pair[2 * t] = w0;   w_pair[2 * t + 1] = w1;
        atomicAdd(&hdr[8 + i0], 1); atomicAdd(&hdr[8 + i1], 1);
        atomicAdd(&esum[i0], w0); atomicAdd(&esum[i1], w1);
    }
}

// ---------------- prefix scan + tile maps (256 & 128) + load-balance loss ----------------
__global__ void prefix_lb_kernel(int* __restrict__ hdr, const float* __restrict__ esum,
                                 float* __restrict__ lb_out) {
    if (threadIdx.x == 0) {
        int run = 0, t256 = 0, t128 = 0;
        for (int e = 0; e < NEXP; e++) {
            int c = hdr[8 + e];
            hdr[16 + e] = run;
            hdr[24 + e] = run;
            int nt2 = (c + 255) >> 8;
            for (int t = 0; t < nt2; t++) {
                int valid = c - t * 256; if (valid > 256) valid = 256;
                hdr[64 + t256++] = e | (valid << 4) | ((run + t * 256) << 16);
            }
            int nt1 = (c + 127) >> 7;
            for (int t = 0; t < nt1; t++) {
                int valid = c - t * 128; if (valid > 128) valid = 128;
                hdr[256 + t128++] = e | (valid << 4) | ((run + t * 128) << 16);
            }
            run += nt2 * 256;
        }
        hdr[0] = t256;
        hdr[1] = t128;
        float mu = 0.f, us[NEXP];
        for (int e = 0; e < NEXP; e++) { us[e] = esum[e] * (1.0f / T_TOK); mu += us[e]; }
        mu *= (1.0f / NEXP);
        float var = 0.f;
        for (int e = 0; e < NEXP; e++) { float d = us[e] - mu; var += d * d; }
        var *= (1.0f / (NEXP - 1));
        lb_out[0] = 0.01f * var;
    }
}

// ---------------- scatter: compact rows + record slot per (token,k) ----------------
__global__ __launch_bounds__(256) void scatter_kernel(
        const int* __restrict__ idx_pair, const float* __restrict__ w_pair,
        int* __restrict__ hdr, int* __restrict__ row_tok, float* __restrict__ row_w,
        int* __restrict__ slot_pair) {
    int t = blockIdx.x * 256 + threadIdx.x;
#pragma unroll
    for (int k = 0; k < 2; k++) {
        int e = idx_pair[2 * t + k];
        int slot = atomicAdd(&hdr[16 + e], 1);
        row_tok[slot] = t;
        row_w[slot] = w_pair[2 * t + k];
        slot_pair[2 * t + k] = slot;
    }
}

// ---------------- transpose+convert: src[E][R][C] fp32 -> dst[E][C'][R] bf16 ----------------
__global__ __launch_bounds__(256) void transpose_bf16_kernel(
        const float* __restrict__ src, unsigned short* __restrict__ dst,
        int R, int C, int colBase, int colsPerE) {
    int e = blockIdx.z;
    int c0 = colBase + blockIdx.x * 64;
    int r0 = blockIdx.y * 64;
    __shared__ float tile[64][65];
    int tx = threadIdx.x & 63, ty = threadIdx.x >> 6;
    const float* s = src + (size_t)e * R * C;
#pragma unroll
    for (int i = 0; i < 16; i++)
        tile[ty + i * 4][tx] = s[(size_t)(r0 + ty + i * 4) * C + c0 + tx];
    __syncthreads();
    unsigned short* d = dst + (size_t)e * colsPerE * R;
#pragma unroll
    for (int i = 0; i < 16; i++)
        d[(size_t)(c0 - colBase + ty + i * 4) * R + r0 + tx] = f2bf(tile[tx][ty + i * 4]);
}

// ---------------- FFN1: 256x256 tile, BK=64, 8 waves, 4-phase pipelined schedule ------------
// LDS (static, 128 KiB): A: [dbuf2][half2][128 rows][64 k] bf16 (64 KiB), then B same (64 KiB).
// Swizzle: 16B-chunk c of row r stored XOR'd: chunk ^= 2*((r>>2)&1)  (st_16x32 family).
// Applied as inverse on the global source (gl_lds dest stays linear) and on the ds_read side.
#define FFN_PHASE(Q, STAGE, WAITC)                                                          \
    {                                                                                       \
        short8 afr[2][2];                                                                   \
        _Pragma("unroll")                                                                   \
        for (int ii = 0; ii < 2; ii++)                                                      \
            _Pragma("unroll")                                                               \
            for (int ks = 0; ks < 2; ks++)                                                  \
                afr[ii][ks] = *(const short8*)(lds + pofs + aoff + (2*(Q)+ii)*2048 + ks*64);\
        STAGE;                                                                              \
        __builtin_amdgcn_s_barrier();                                                       \
        __builtin_amdgcn_s_waitcnt(WAITCNT_LGKM0);                                          \
        __builtin_amdgcn_s_setprio(1);                                                      \
        _Pragma("unroll")                                                                   \
        for (int ks = 0; ks < 2; ks++)                                                      \
            _Pragma("unroll")                                                               \
            for (int ii = 0; ii < 2; ii++)                                                  \
                _Pragma("unroll")                                                           \
                for (int nj = 0; nj < 4; nj++)                                              \
                    acc[2*(Q)+ii][nj] = __builtin_amdgcn_mfma_f32_16x16x32_bf16(            \
                        afr[ii][ks], bfr[nj][ks], acc[2*(Q)+ii][nj], 0, 0, 0);              \
        __builtin_amdgcn_s_setprio(0);                                                      \
        WAITC;                                                                              \
        __builtin_amdgcn_s_barrier();                                                       \
    }

__global__ __launch_bounds__(512, 2) void ffn1_kernel(
        const unsigned short* __restrict__ Xb, const unsigned short* __restrict__ W1T,
        const float* __restrict__ b1, const int* __restrict__ hdr,
        const int* __restrict__ row_tok, unsigned short* __restrict__ H,
        int chunkF, int fBase, int fsh) {
    __shared__ __attribute__((aligned(16))) char lds[131072];
    int lin = blockIdx.x;
    int xcd = lin & 7, pos = lin >> 3;
    int tile = xcd * 9 + (pos >> fsh);
    int fidx = pos & ((1 << fsh) - 1);
    if (tile >= hdr[0]) return;
    int tm = hdr[64 + tile];
    int e = tm & 15, valid = (tm >> 4) & 511, base = tm >> 16;
    int f0 = fidx * 256;

    int tid = threadIdx.x;
    int lane = tid & 63;
    int w = tid >> 6;            // 0..7
    int wm = w >> 2, wn = w & 3; // 2 M-halves x 4 N-quarters

    // ---- staging sources: per half-tile this thread issues 2 x 16B ----
    int srow = tid >> 3;         // 0..63
    int sc = tid & 7;
    int csrc = sc ^ (((srow >> 2) & 1) << 1);   // inverse swizzle on global source
    const char* gA[4];
    const char* gB[4];
#pragma unroll
    for (int h = 0; h < 2; h++)
#pragma unroll
        for (int i = 0; i < 2; i++) {
            int r = h * 128 + i * 64 + srow;
            int rc = r < valid ? r : valid - 1;
            gA[h * 2 + i] = (const char*)Xb + (size_t)row_tok[base + rc] * (DH * 2) + csrc * 16;
            gB[h * 2 + i] = (const char*)W1T + ((size_t)e * chunkF + f0 + r) * (DH * 2) + csrc * 16;
        }
    const int NT = DH / 64;      // 16 K-tiles

    auto stageA = [&](int t2, int h) {
        if (t2 >= NT) return;
        char* d = lds + (t2 & 1) * 32768 + h * 16384 + w * 1024;
        size_t ko = (size_t)t2 * 128;
        gl_lds16(gA[h * 2 + 0] + ko, d);
        gl_lds16(gA[h * 2 + 1] + ko, d + 8192);
    };
    auto stageB = [&](int t2, int h) {
        if (t2 >= NT) return;
        char* d = lds + 65536 + (t2 & 1) * 32768 + h * 16384 + w * 1024;
        size_t ko = (size_t)t2 * 128;
        gl_lds16(gB[h * 2 + 0] + ko, d);
        gl_lds16(gB[h * 2 + 1] + ko, d + 8192);
    };

    // ---- fragment read offsets (swizzled on the read side) ----
    int l15 = lane & 15, lg = lane >> 4;
    int lgx = lg ^ (((l15 >> 2) & 1) << 1);
    int aoff = wm * 16384 + l15 * 128 + lgx * 16;                          // + mi*2048 + ks*64
    int boff = 65536 + (wn >> 1) * 16384 + ((wn & 1) * 64 + l15) * 128 + lgx * 16; // + nj*2048 + ks*64

    f32x4 acc[8][4];
#pragma unroll
    for (int i = 0; i < 8; i++)
#pragma unroll
        for (int j = 0; j < 4; j++) acc[i][j] = (f32x4)(0.f);

    // ---- prologue: tile0 fully + B(tile1); vmcnt(4) leaves B(1) in flight ----
    stageA(0, 0); stageA(0, 1); stageB(0, 0); stageB(0, 1);
    stageB(1, 0); stageB(1, 1);
    __builtin_amdgcn_s_waitcnt(WAITCNT_VM4);
    __builtin_amdgcn_s_barrier();

    for (int t = 0; t < NT; t++) {
        int pofs = (t & 1) * 32768;
        short8 bfr[4][2];
#pragma unroll
        for (int nj = 0; nj < 4; nj++)
#pragma unroll
            for (int ks = 0; ks < 2; ks++)
                bfr[nj][ks] = *(const short8*)(lds + pofs + boff + nj * 2048 + ks * 64);
        FFN_PHASE(0, stageA(t + 1, 0), ((void)0));
        FFN_PHASE(1, stageA(t + 1, 1), ((void)0));
        FFN_PHASE(2, stageB(t + 2, 0), ((void)0));
        FFN_PHASE(3, stageB(t + 2, 1),
                  if (t < NT - 2) __builtin_amdgcn_s_waitcnt(WAITCNT_VM4);
                  else            __builtin_amdgcn_s_waitcnt(WAITCNT_VM0));
    }

    // ---- epilogue: bias + gelu + bf16 store ----
    const float* bp = b1 + (size_t)e * DFFN + fBase + f0;
#pragma unroll
    for (int mi = 0; mi < 8; mi++) {
#pragma unroll
        for (int r = 0; r < 4; r++) {
            int mm = wm * 128 + mi * 16 + lg * 4 + r;
            if (mm < valid) {
                unsigned short* hrow = H + (size_t)(base + mm) * chunkF + f0 + wn * 64;
#pragma unroll
                for (int nj = 0; nj < 4; nj++) {
                    int cc2 = nj * 16 + l15;
                    float v = acc[mi][nj][r] + bp[wn * 64 + cc2];
                    v = 0.5f * v * (1.0f + erff(v * 0.70710678118f));
                    hrow[cc2] = f2bf(v);
                }
            }
        }
    }
}

// ---------------- FFN2: Y[slot] (+)= H @ W2T^T (+ b2), dbuf + XCD-chunked (128^2) ----------
__global__ __launch_bounds__(256) void ffn2_kernel(
        const unsigned short* __restrict__ H, const unsigned short* __restrict__ W2T,
        const float* __restrict__ b2, const int* __restrict__ hdr,
        float* __restrict__ Y, int chunkF, int cBase, int firstChunk) {
    int lin = blockIdx.x;
    int xcd = lin & 7, pos = lin >> 3;
    int tile = xcd * 17 + (pos >> 3);
    int didx = pos & 7;
    if (tile >= hdr[1]) return;
    int tm = hdr[256 + tile];
    int e = tm & 15, valid = (tm >> 4) & 255, base = tm >> 16;
    int d0 = didx * 128;

    __shared__ unsigned short Alds[2 * 128 * 32];
    __shared__ unsigned short Blds[2 * 128 * 32];

    int tid = threadIdx.x;
    int lane = tid & 63, w = tid >> 6;
    int rloc = lane >> 2, cc = lane & 3;
    int r0 = w * 16 + rloc, r1 = 64 + w * 16 + rloc;
    int cl0 = r0 < valid ? r0 : valid - 1;
    int cl1 = r1 < valid ? r1 : valid - 1;
    const char* gA0 = (const char*)H + (size_t)(base + cl0) * chunkF * 2 + (cc ^ swz(r0)) * 16;
    const char* gA1 = (const char*)H + (size_t)(base + cl1) * chunkF * 2 + (cc ^ swz(r1)) * 16;
    const char* gB0 = (const char*)W2T + ((size_t)(e * DH + d0 + r0) * DFFN + cBase) * 2 + (cc ^ swz(r0)) * 16;
    const char* gB1 = (const char*)W2T + ((size_t)(e * DH + d0 + r1) * DFFN + cBase) * 2 + (cc ^ swz(r1)) * 16;
    int lo0 = (w * 16) * 64, lo1 = (64 + w * 16) * 64;

    int wm = (w & 1) * 64, wn = (w >> 1) * 64;
    int lr = lane & 15, lg = lane >> 4;
    int offA[4], offB[4];
#pragma unroll
    for (int i = 0; i < 4; i++) {
        int rr = wm + i * 16 + lr;
        offA[i] = rr * 32 + (lg ^ swz(rr)) * 8;
        int nn = wn + i * 16 + lr;
        offB[i] = nn * 32 + (lg ^ swz(nn)) * 8;
    }

    f32x4 acc[4][4];
#pragma unroll
    for (int i = 0; i < 4; i++)
#pragma unroll
        for (int j = 0; j < 4; j++) acc[i][j] = (f32x4)(0.f);

    auto issue = [&](int pb) {
        char* la = (char*)Alds + pb * 8192;
        char* lb = (char*)Blds + pb * 8192;
        gl_lds16(gA0, la + lo0); gl_lds16(gA1, la + lo1);
        gl_lds16(gB0, lb + lo0); gl_lds16(gB1, lb + lo1);
        gA0 += 64; gA1 += 64; gB0 += 64; gB1 += 64;
    };

    issue(0);
    const int steps = chunkF / 32;
    for (int kk = 0; kk < steps; kk++) {
        int p = kk & 1;
        issue(p ^ 1);
        __builtin_amdgcn_s_waitcnt(WAITCNT_VM4);
        __builtin_amdgcn_s_barrier();
        const unsigned short* Ab = Alds + p * 4096;
        const unsigned short* Bb = Blds + p * 4096;
        short8 af[4], bf[4];
#pragma unroll
        for (int i = 0; i < 4; i++) af[i] = *(const short8*)&Ab[offA[i]];
#pragma unroll
        for (int j = 0; j < 4; j++) bf[j] = *(const short8*)&Bb[offB[j]];
#pragma unroll
        for (int i = 0; i < 4; i++)
#pragma unroll
            for (int j = 0; j < 4; j++)
                acc[i][j] = __builtin_amdgcn_mfma_f32_16x16x32_bf16(af[i], bf[j], acc[i][j], 0, 0, 0);
        __builtin_amdgcn_s_barrier();
    }
    __builtin_amdgcn_s_waitcnt(WAITCNT_VM0);

#pragma unroll
    for (int i = 0; i < 4; i++) {
#pragma unroll
        for (int r = 0; r < 4; r++) {
            int mm = wm + i * 16 + lg * 4 + r;
            if (mm < valid) {
                float* yrow = Y + (size_t)(base + mm) * DH + d0;
#pragma unroll
                for (int j = 0; j < 4; j++) {
                    int n = wn + j * 16 + lr;
                    float v = acc[i][j][r];
                    if (firstChunk) yrow[n] = v + b2[e * DH + d0 + n];
                    else            yrow[n] += v;
                }
            }
        }
    }
}

// ---------------- combine: out[t] = w0*Y[s0] + w1*Y[s1] ----------------
__global__ __launch_bounds__(256) void combine_kernel(
        const float* __restrict__ Y, const int* __restrict__ slot_pair,
        const float* __restrict__ w_pair, float* __restrict__ out) {
    int t = blockIdx.x;
    int s0 = slot_pair[2 * t], s1 = slot_pair[2 * t + 1];
    float w0 = w_pair[2 * t], w1 = w_pair[2 * t + 1];
    const float4* y0 = (const float4*)(Y + (size_t)s0 * DH);
    const float4* y1 = (const float4*)(Y + (size_t)s1 * DH);
    float4* o = (float4*)(out + (size_t)t * DH);
    int i = threadIdx.x;
    float4 a = y0[i], b = y1[i];
    float4 r;
    r.x = w0 * a.x + w1 * b.x;
    r.y = w0 * a.y + w1 * b.y;
    r.z = w0 * a.z + w1 * b.z;
    r.w = w0 * a.w + w1 * b.w;
    o[i] = r;
}

extern "C" void kernel_launch(void* const* d_in, const int* in_sizes, int n_in,
                              void* d_out, int out_size, void* d_ws, size_t ws_size,
                              hipStream_t stream) {
    const float* x  = (const float*)d_in[0];
    const float* Wg = (const float*)d_in[1];
    const float* W1 = (const float*)d_in[2];
    const float* b1 = (const float*)d_in[3];
    const float* W2 = (const float*)d_in[4];
    const float* b2 = (const float*)d_in[5];
    float* out = (float*)d_out;
    char* ws = (char*)d_ws;

    int* hdr       = (int*)ws;
    float* esum    = (float*)(hdr + 32);
    int* idx_pair  = (int*)(ws + WS_IDX);
    float* w_pair  = (float*)(ws + WS_WPAIR);
    int* slot_pair = (int*)(ws + WS_SLOT);
    int* row_tok   = (int*)(ws + WS_ROWTOK);
    float* row_w   = (float*)(ws + WS_ROWW);
    unsigned short* Xb = (unsigned short*)(ws + WS_XB);

    size_t off_w2t = WS_XB + (size_t)T_TOK * DH * 2;                 // +16 MB
    size_t off_y   = off_w2t + (size_t)NEXP * DH * DFFN * 2;         // +64 MB
    size_t off_w1t = off_y + (size_t)MAXROWS * DH * 4;               // +72 MB
    int NC = 1;
    while (NC < 8) {
        size_t need = off_w1t + ((size_t)NEXP * DFFN * DH * 2) / NC
                              + ((size_t)MAXROWS * DFFN * 2) / NC + 4096;
        if (need <= ws_size) break;
        NC *= 2;
    }
    int chunkF = DFFN / NC;
    int fcount1 = chunkF >> 8;            // 256-wide f-tiles for ffn1
    int fsh1 = __builtin_ctz(fcount1);
    unsigned short* W2T = (unsigned short*)(ws + off_w2t);
    float* Y            = (float*)(ws + off_y);
    unsigned short* W1T = (unsigned short*)(ws + off_w1t);
    unsigned short* Hc  = (unsigned short*)(ws + off_w1t + (size_t)NEXP * chunkF * DH * 2);

    hipMemsetAsync(ws, 0, 1024, stream);

    gate_kernel<<<T_TOK / 4, 256, 0, stream>>>(x, Wg, hdr, esum, idx_pair, w_pair, Xb);
    prefix_lb_kernel<<<1, 64, 0, stream>>>(hdr, esum, out + (size_t)T_TOK * DH);
    scatter_kernel<<<T_TOK / 256, 256, 0, stream>>>(idx_pair, w_pair, hdr, row_tok, row_w,
                                                    slot_pair);
    // W2 [E][DFFN][DH] -> W2T [E][DH][DFFN] bf16
    transpose_bf16_kernel<<<dim3(DH / 64, DFFN / 64, NEXP), 256, 0, stream>>>(
        W2, W2T, DFFN, DH, 0, DH);

    for (int c = 0; c < NC; c++) {
        transpose_bf16_kernel<<<dim3(chunkF / 64, DH / 64, NEXP), 256, 0, stream>>>(
            W1, W1T, DH, DFFN, c * chunkF, chunkF);
        ffn1_kernel<<<MAXT256 * fcount1, 512, 0, stream>>>(
            Xb, W1T, b1, hdr, row_tok, Hc, chunkF, c * chunkF, fsh1);
        ffn2_kernel<<<MAXT * 8, 256, 0, stream>>>(
            Hc, W2T, b2, hdr, Y, chunkF, c * chunkF, c == 0);
    }
    combine_kernel<<<T_TOK, 256, 0, stream>>>(Y, slot_pair, w_pair, out);
}